// Round 13
// baseline (267.842 us; speedup 1.0000x reference)
//
#include <hip/hip_runtime.h>
#include <stdint.h>

// KNN K=16 over x (B=2, N=8192, D=64) f32. Output int32 (2,B,N,K): nn_idx, center_idx.
// Pipeline: split_k (bf16 hi/lo + norms) -> tau_p (MFMA depth-1 min-ladders over
// 2048-sample, filter-template) -> tau_m (merge -> per-query provable threshold) ->
// filter_k (MFMA bf16 3-term split distance, double-buffered async staging, A in
// VGPRs, BALLOT-compacted branchless accepts, no atomics) -> rerank_k (exact f64).
// Threshold correctness: 16th-smallest of ANY subset of sample keys >= sample-16th
// >= true d16 (pigeonhole); slop covers bf16-split approx error, so all true
// top-16 provably survive the filter.
constexpr int N_    = 8192;
constexpr int D_    = 64;
constexpr int K_    = 16;
constexpr int NQ    = 16384;          // 2*8192
constexpr int MS    = 8;              // m-superblocks per batch (1024 m each)
constexpr int CAP_H = 20;             // survivor cap per (query, superblock, wm-half): E=4, +7 sigma
constexpr int CAPB  = 2 * CAP_H;      // global slot per (query, superblock) = 40
constexpr float SLOP = 0.012f;        // per-stage slop >> 2*eps(bf16-split ~1.3e-3)

typedef __attribute__((ext_vector_type(8))) short bf16x8;
typedef __attribute__((ext_vector_type(4))) float f32x4;

template<int JN>
__device__ __forceinline__ void topk_insertf(float (&key)[JN], float nk) {
    if (nk < key[JN - 1]) {
        bool c[JN];
#pragma unroll
        for (int j = 0; j < JN; ++j) c[j] = nk < key[j];
#pragma unroll
        for (int j = JN - 1; j >= 1; --j)
            key[j] = c[j - 1] ? key[j - 1] : (c[j] ? nk : key[j]);
        key[0] = c[0] ? nk : key[0];
    }
}

__device__ __forceinline__ unsigned short bf16_rne(float f) {
    uint32_t u = __float_as_uint(f);
    return (unsigned short)((u + 0x7FFFu + ((u >> 16) & 1u)) >> 16);   // no NaN in data
}

// async 16B global -> LDS (no VGPR round-trip). Dest = wave-uniform base + lane*16.
__device__ __forceinline__ void gl_lds16(const void* g, void* l) {
    __builtin_amdgcn_global_load_lds(
        (const __attribute__((address_space(1))) unsigned int*)g,
        (__attribute__((address_space(3))) unsigned int*)l, 16, 0, 0);
}

#define SWZ(r, s) (((r) << 7) + ((((s) ^ ((r) & 7))) << 4))

// K1: bf16 hi/lo split + squared norms. 16 lanes per row (coalesced). grid = 1024.
__global__ void __launch_bounds__(256) split_k(const float* __restrict__ x,
                                               unsigned short* __restrict__ xh,
                                               unsigned short* __restrict__ xl,
                                               float* __restrict__ nrm) {
    const int t = blockIdx.x * 256 + (int)threadIdx.x;    // one float4 per thread
    const int row = t >> 4, seg = t & 15;
    const float4 v = reinterpret_cast<const float4*>(x)[t];
    float f[4] = {v.x, v.y, v.z, v.w};
    unsigned short h[4], l[4];
    float sq = 0.f;
#pragma unroll
    for (int j = 0; j < 4; ++j) {
        sq = fmaf(f[j], f[j], sq);
        h[j] = bf16_rne(f[j]);
        float hf = __uint_as_float((uint32_t)h[j] << 16);
        l[j] = bf16_rne(f[j] - hf);                       // residual exact in f32
    }
    sq += __shfl_xor(sq, 1, 16); sq += __shfl_xor(sq, 2, 16);
    sq += __shfl_xor(sq, 4, 16); sq += __shfl_xor(sq, 8, 16);
    if (seg == 0) nrm[row] = sq;
    ushort4 hv = {h[0], h[1], h[2], h[3]}, lv = {l[0], l[1], l[2], l[3]};
    reinterpret_cast<ushort4*>(xh)[t] = hv;
    reinterpret_cast<ushort4*>(xl)[t] = lv;
}

// K2a: MFMA tau partials, filter-template. Block = 64 q x 512 samples (8 chunks
// of 64, DMA double-buffered). Depth-1 min ladder per (lane, q): subset of sample
// keys -> pigeonhole-valid; tau loosens by ~1 rank (negligible survivors).
// grid = 256 q-tiles x 4 sample-quarters = 1024 blocks (4 blocks/CU at 34.5 KB).
__global__ void __launch_bounds__(256, 4) tau_p(const unsigned short* __restrict__ xh,
                                                const unsigned short* __restrict__ xl,
                                                const float* __restrict__ nrm,
                                                float* __restrict__ part) {
    __shared__ alignas(16) unsigned short Bd[2][128 * 64];  // 2 x 16 KB (64 hi + 64 lo rows)
    __shared__ alignas(16) float nrmS[512];                 // 2 KB sample norms
    const int tid = (int)threadIdx.x;
    const int bid = (int)blockIdx.x;
    const int qb  = bid >> 2, sh = bid & 3;                 // q-tile, sample-quarter
    const int q0g = qb * 64;
    const int b   = q0g >> 13;                              // uniform (64 | 8192)
    const int q0l = q0g & (N_ - 1);
    const int s0  = sh * 512;                               // sample base within batch
    const unsigned short* __restrict__ xhb = xh + (size_t)b * N_ * D_;
    const unsigned short* __restrict__ xlb = xl + (size_t)b * N_ * D_;
    const float* __restrict__ nb = nrm + b * N_;
    const int w = tid >> 6, lane = tid & 63;
    const int wq = w >> 1, wm = w & 1;                      // 32q x 32m wave subtile
    const int l15 = lane & 15, quad = lane >> 4;

    // A fragments (q rows) straight from global into VGPRs (one-time gathers)
    bf16x8 Afh[2][2], Afl[2][2];
#pragma unroll
    for (int half = 0; half < 2; ++half) {
        const int ko = (half * 4 + quad) << 4;              // byte offset in row
#pragma unroll
        for (int tm = 0; tm < 2; ++tm) {
            const int r = q0l + wq * 32 + tm * 16 + l15;
            Afh[half][tm] = *(const bf16x8*)((const char*)(xhb + (size_t)r * D_) + ko);
            Afl[half][tm] = *(const bf16x8*)((const char*)(xlb + (size_t)r * D_) + ko);
        }
    }
    {                                                       // async stage chunk 0 -> Bd[0]
#pragma unroll
        for (int k = 0; k < 4; ++k) {
            int u = k * 256 + tid, r = u >> 3, sg = (u & 7) ^ (r & 7);
            const unsigned short* src = (r < 64) ? xhb + (size_t)(s0 + r) * D_
                                                 : xlb + (size_t)(s0 + r - 64) * D_;
            gl_lds16((const char*)src + (sg << 4), (char*)Bd[0] + (k << 12) + (w << 10));
        }
    }
    *(float2*)(nrmS + tid * 2) = *(const float2*)(nb + s0 + tid * 2);

    float lad[8];
#pragma unroll
    for (int j = 0; j < 8; ++j) lad[j] = __builtin_inff();
    __syncthreads();                                        // chunk 0 + nrmS visible

    for (int mc = 0; mc < 8; ++mc) {
        const int cur = mc & 1;
        if (mc < 7) {                                       // async stage next chunk
            const int m0n = s0 + (mc + 1) * 64;
#pragma unroll
            for (int k = 0; k < 4; ++k) {
                int u = k * 256 + tid, r = u >> 3, sg = (u & 7) ^ (r & 7);
                const unsigned short* src = (r < 64) ? xhb + (size_t)(m0n + r) * D_
                                                     : xlb + (size_t)(m0n + r - 64) * D_;
                gl_lds16((const char*)src + (sg << 4), (char*)Bd[1 - cur] + (k << 12) + (w << 10));
            }
        }
        f32x4 acc[2][2] = {};
#pragma unroll
        for (int half = 0; half < 2; ++half) {
            const int seg = half * 4 + quad;
            bf16x8 bfh[2], bfl[2];
#pragma unroll
            for (int tn = 0; tn < 2; ++tn) {
                bfh[tn] = *(const bf16x8*)((const char*)Bd[cur] + SWZ(wm * 32 + tn * 16 + l15, seg));
                bfl[tn] = *(const bf16x8*)((const char*)Bd[cur] + SWZ(64 + wm * 32 + tn * 16 + l15, seg));
            }
#pragma unroll
            for (int tm = 0; tm < 2; ++tm)
#pragma unroll
                for (int tn = 0; tn < 2; ++tn) {
                    acc[tm][tn] = __builtin_amdgcn_mfma_f32_16x16x32_bf16(Afh[half][tm], bfh[tn], acc[tm][tn], 0, 0, 0);
                    acc[tm][tn] = __builtin_amdgcn_mfma_f32_16x16x32_bf16(Afh[half][tm], bfl[tn], acc[tm][tn], 0, 0, 0);
                    acc[tm][tn] = __builtin_amdgcn_mfma_f32_16x16x32_bf16(Afl[half][tm], bfh[tn], acc[tm][tn], 0, 0, 0);
                }
        }
        // epilogue: C/D col=lane&15 (m), row=quad*4+reg (q); depth-1 min ladder
#pragma unroll
        for (int tn = 0; tn < 2; ++tn) {
            const float nm = nrmS[mc * 64 + wm * 32 + tn * 16 + l15];
#pragma unroll
            for (int tm = 0; tm < 2; ++tm)
#pragma unroll
                for (int reg = 0; reg < 4; ++reg)
                    lad[tm * 4 + reg] = fminf(lad[tm * 4 + reg],
                                              fmaf(-2.f, acc[tm][tn][reg], nm));
        }
        __syncthreads();                                    // seals Bd[cur] reads + DMA drain
    }
    // part[q][128]: offset = sh*32 + wm*16 + l15 (4sh x 2wm x 16 lanes = 128/query)
#pragma unroll
    for (int tm = 0; tm < 2; ++tm)
#pragma unroll
        for (int reg = 0; reg < 4; ++reg) {
            const int q = q0g + wq * 32 + tm * 16 + quad * 4 + reg;
            part[(size_t)q * 128 + sh * 32 + wm * 16 + l15] = lad[tm * 4 + reg];
        }
}

// K2b: merge 128 partials/query -> tau. Thread per query. grid = NQ/64 = 256.
__global__ void __launch_bounds__(64) tau_m(const float* __restrict__ part,
                                            float* __restrict__ tau) {
    const int q = blockIdx.x * 64 + (int)threadIdx.x;
    const float4* p = reinterpret_cast<const float4*>(part + (size_t)q * 128);
    float key[K_];
#pragma unroll
    for (int j = 0; j < K_; ++j) key[j] = __builtin_inff();
    for (int i = 0; i < 32; ++i) {
        float4 v = p[i];
        topk_insertf<K_>(key, v.x); topk_insertf<K_>(key, v.y);
        topk_insertf<K_>(key, v.z); topk_insertf<K_>(key, v.w);
    }
    tau[q] = key[15] + SLOP;
}

// K3: MFMA filter. Block = 128q x 1024m, 16 chunks of 64m, double-buffered async
// staging. A fragments + thresholds in VGPRs (no A LDS -> 47.6 KB -> 3 blocks/CU).
// Accepts via BALLOT compaction: per key, per-quad 16-bit mask slice; position =
// replicated VGPR counter + popcount-below-lane; one predicated ds_write. No
// atomics, no branches, no waitcnt round-trips (R12: atomic-return stalls).
// Per-wm private lists, concatenated at flush. grid = 2*64*8 = 1024 blocks.
__global__ void __launch_bounds__(256, 3) filter_k(const unsigned short* __restrict__ xh,
                                                   const unsigned short* __restrict__ xl,
                                                   const float* __restrict__ nrm,
                                                   const float* __restrict__ tau,
                                                   unsigned short* __restrict__ cnt_pb,
                                                   unsigned short* __restrict__ buf2) {
    __shared__ alignas(16) unsigned short Bd[2][128 * 64];  // 2 x 16 KB (64 hi + 64 lo rows)
    __shared__ alignas(16) float nrmS[1024];                // 4 KB superblock norms
    __shared__ unsigned short lists[2][128][CAP_H];         // 10 KB (wm-private)
    __shared__ unsigned short cnt2[2][128];                 // 0.5 KB
    const int tid = (int)threadIdx.x;
    const int bid = (int)blockIdx.x;
    const int b  = bid >> 9;
    const int qt = (bid >> 3) & 63;
    const int ms = bid & 7;
    const int q0 = qt * 128;
    const unsigned short* __restrict__ xhb = xh + (size_t)b * N_ * D_;
    const unsigned short* __restrict__ xlb = xl + (size_t)b * N_ * D_;
    const float* __restrict__ nb = nrm + b * N_;
    const int w = tid >> 6, lane = tid & 63;
    const int wq = w >> 1, wm = w & 1;                      // 64q x 32m wave subtile
    const int l15 = lane & 15, quad = lane >> 4;

    // A fragments straight from global into VGPRs (one-time gathers, L2-hit)
    bf16x8 Afh[2][4], Afl[2][4];
#pragma unroll
    for (int half = 0; half < 2; ++half) {
        const int ko = (half * 4 + quad) << 4;
#pragma unroll
        for (int tm = 0; tm < 4; ++tm) {
            const int r = q0 + wq * 64 + tm * 16 + l15;
            Afh[half][tm] = *(const bf16x8*)((const char*)(xhb + (size_t)r * D_) + ko);
            Afl[half][tm] = *(const bf16x8*)((const char*)(xlb + (size_t)r * D_) + ko);
        }
    }
    f32x4 t4v[4];                                           // thresholds in VGPRs
#pragma unroll
    for (int tm = 0; tm < 4; ++tm)
        t4v[tm] = *(const f32x4*)(tau + (b << 13) + q0 + wq * 64 + tm * 16 + quad * 4) + SLOP;

    {                                                       // async stage chunk 0 -> Bd[0]
        const int m0 = ms * 1024;
#pragma unroll
        for (int k = 0; k < 4; ++k) {
            int u = k * 256 + tid, r = u >> 3, sg = (u & 7) ^ (r & 7);
            const unsigned short* src = (r < 64) ? xhb + (size_t)(m0 + r) * D_
                                                 : xlb + (size_t)(m0 + r - 64) * D_;
            gl_lds16((const char*)src + (sg << 4), (char*)Bd[0] + (k << 12) + (w << 10));
        }
    }
    *(float4*)(nrmS + tid * 4) = *(const float4*)(nb + ms * 1024 + tid * 4);
    if (tid < 128) { cnt2[0][tid] = 0; cnt2[1][tid] = 0; }

    const unsigned long long qmask = 0xFFFFull << (quad * 16);
    const unsigned lowm = (1u << l15) - 1u;
    int cq[16];                                             // replicated per-quad counters
#pragma unroll
    for (int j = 0; j < 16; ++j) cq[j] = 0;
    __syncthreads();                                        // chunk 0 + nrmS visible

    for (int mc = 0; mc < 16; ++mc) {
        const int cur = mc & 1;
        if (mc < 15) {                                      // async stage next chunk
            const int m0n = ms * 1024 + (mc + 1) * 64;
#pragma unroll
            for (int k = 0; k < 4; ++k) {
                int u = k * 256 + tid, r = u >> 3, sg = (u & 7) ^ (r & 7);
                const unsigned short* src = (r < 64) ? xhb + (size_t)(m0n + r) * D_
                                                     : xlb + (size_t)(m0n + r - 64) * D_;
                gl_lds16((const char*)src + (sg << 4), (char*)Bd[1 - cur] + (k << 12) + (w << 10));
            }
        }
        f32x4 acc[4][2] = {};
#pragma unroll
        for (int half = 0; half < 2; ++half) {
            const int seg = half * 4 + quad;
            bf16x8 bfh[2], bfl[2];
#pragma unroll
            for (int tn = 0; tn < 2; ++tn) {
                bfh[tn] = *(const bf16x8*)((const char*)Bd[cur] + SWZ(wm * 32 + tn * 16 + l15, seg));
                bfl[tn] = *(const bf16x8*)((const char*)Bd[cur] + SWZ(64 + wm * 32 + tn * 16 + l15, seg));
            }
#pragma unroll
            for (int tm = 0; tm < 4; ++tm)
#pragma unroll
                for (int tn = 0; tn < 2; ++tn) {
                    acc[tm][tn] = __builtin_amdgcn_mfma_f32_16x16x32_bf16(Afh[half][tm], bfh[tn], acc[tm][tn], 0, 0, 0);
                    acc[tm][tn] = __builtin_amdgcn_mfma_f32_16x16x32_bf16(Afh[half][tm], bfl[tn], acc[tm][tn], 0, 0, 0);
                    acc[tm][tn] = __builtin_amdgcn_mfma_f32_16x16x32_bf16(Afl[half][tm], bfh[tn], acc[tm][tn], 0, 0, 0);
                }
        }
        // epilogue: C/D col=lane&15 (m), row=quad*4+reg (q); ballot-compacted accepts
#pragma unroll
        for (int tn = 0; tn < 2; ++tn) {
            const int mloc = wm * 32 + tn * 16 + l15;        // m within chunk
            const float nm = nrmS[mc * 64 + mloc];
            const unsigned short mid = (unsigned short)(ms * 1024 + mc * 64 + mloc);
#pragma unroll
            for (int tm = 0; tm < 4; ++tm)
#pragma unroll
                for (int reg = 0; reg < 4; ++reg) {
                    const float keyf = fmaf(-2.f, acc[tm][tn][reg], nm);
                    const bool pred = keyf <= t4v[tm][reg];
                    const unsigned long long m64 = __ballot(pred);
                    const unsigned mv = (unsigned)((m64 & qmask) >> (quad * 16));
                    const int li = tm * 4 + reg;
                    if (pred) {
                        const int pos = cq[li] + __popc(mv & lowm);
                        if (pos < CAP_H)
                            lists[wm][wq * 64 + tm * 16 + quad * 4 + reg][pos] = mid;
                    }
                    cq[li] += __popc(mv);
                }
        }
        __syncthreads();                                    // seals Bd[cur] reads + DMA drain
    }
    if (l15 == 0) {                                         // counters -> LDS (replicated/quad)
#pragma unroll
        for (int tm = 0; tm < 4; ++tm)
#pragma unroll
            for (int reg = 0; reg < 4; ++reg) {
                int c = cq[tm * 4 + reg];
                cnt2[wm][wq * 64 + tm * 16 + quad * 4 + reg] =
                    (unsigned short)(c < CAP_H ? c : CAP_H);
            }
    }
    __syncthreads();
    if (tid < 128) {                                        // flush: concat wm halves
        const int q = (b << 13) + q0 + tid;
        const int c0 = cnt2[0][tid], c1 = cnt2[1][tid];
        cnt_pb[(size_t)q * MS + ms] = (unsigned short)(c0 + c1);
        unsigned short* dst = buf2 + ((size_t)q * MS + ms) * CAPB;
        for (int i = 0; i < c0; ++i) dst[i] = lists[0][tid][i];
        for (int i = 0; i < c1; ++i) dst[c0 + i] = lists[1][tid][i];
    }
}

// K4: exact f64 rerank, wave-per-query. Each lane computes one candidate's full
// 64-dim f64 distance (gather loads + LDS-broadcast Q); selection via 64-lane
// bitonic sort of packed u64 (dist,id) keys: keep top-16 in lanes 0-15, refill
// 48, resort. block 256 = 4 waves = 4 queries; grid = NQ/4 = 4096.
__global__ void __launch_bounds__(256) rerank_k(const float* __restrict__ x,
                                                const unsigned short* __restrict__ cnt_pb,
                                                const unsigned short* __restrict__ buf2,
                                                int* __restrict__ out) {
    __shared__ float Qs[4 * 64];                           // 1 KB query rows
    __shared__ unsigned short ids[4 * MS * CAPB];          // 2.5 KB compacted survivors
    const int tid = (int)threadIdx.x;
    const int w = tid >> 6, lane = tid & 63;
    const int q = blockIdx.x * 4 + w;
    const int b = q >> 13, n = q & (N_ - 1);
    const float* __restrict__ xb = x + (size_t)b * N_ * D_;
    Qs[w * 64 + lane] = xb[(size_t)n * D_ + lane];

    int off[MS + 1]; off[0] = 0;                           // all lanes compute same
#pragma unroll
    for (int ms = 0; ms < MS; ++ms) {
        int c = (int)cnt_pb[(size_t)q * MS + ms]; c = c < CAPB ? c : CAPB;
        off[ms + 1] = off[ms] + c;
    }
    const int total = off[MS];                             // >= 16 guaranteed (true top-16 pass)
    for (int idx = lane; idx < total; idx += 64) {         // compact ids into LDS
        int ms = 0;
#pragma unroll
        for (int t = 1; t < MS; ++t) ms += (idx >= off[t]) ? 1 : 0;
        ids[(w * MS) * CAPB + idx] = buf2[((size_t)q * MS + ms) * CAPB + (idx - off[ms])];
    }
    __syncthreads();

    unsigned long long v = ~0ull;
    int consumed = 0;
    bool first = true;
    while (first || consumed < total) {
        const int myIdx = first ? lane : consumed + lane - 16;
        const bool take = (first || lane >= 16) && myIdx < total;
        unsigned long long nk = ~0ull;
        if (take) {
            const int id = (int)ids[(w * MS) * CAPB + myIdx];
            const float* __restrict__ crow = xb + (size_t)id * D_;
            double a0 = 0.0, a1 = 0.0, a2 = 0.0, a3 = 0.0;
#pragma unroll
            for (int j = 0; j < 16; ++j) {
                const float4 c  = *(const float4*)(crow + j * 4);        // per-lane gather
                const float4 qv = *(const float4*)(Qs + w * 64 + j * 4); // uniform -> broadcast
                double d0 = (double)qv.x - (double)c.x; a0 = fma(d0, d0, a0);
                double d1 = (double)qv.y - (double)c.y; a1 = fma(d1, d1, a1);
                double d2 = (double)qv.z - (double)c.z; a2 = fma(d2, d2, a2);
                double d3 = (double)qv.w - (double)c.w; a3 = fma(d3, d3, a3);
            }
            double s = (a0 + a1) + (a2 + a3);
            // s >= 0 -> f64 bits order-preserving; low 13 mantissa bits carry the id
            // for exact (dist, id) lexicographic compare (ties -> lower id).
            nk = ((unsigned long long)__double_as_longlong(s) & ~0x1FFFull) | (unsigned)id;
        }
        if (first || lane >= 16) v = nk;                   // lanes 0-15 keep running top-16
        // 64-lane bitonic sort ascending (21 steps)
#pragma unroll
        for (int k = 2; k <= 64; k <<= 1)
#pragma unroll
            for (int j = k >> 1; j > 0; j >>= 1) {
                unsigned long long o = __shfl_xor(v, j, 64);
                const bool keepmin = (((lane & k) == 0) == ((lane & j) == 0));
                unsigned long long mn = v < o ? v : o;
                unsigned long long mx = v < o ? o : v;
                v = keepmin ? mn : mx;
            }
        consumed += first ? 64 : 48;
        first = false;
    }
    if (lane < K_) {
        out[(size_t)q * K_ + lane]                   = (int)(v & 0x1FFFull);  // nn_idx
        out[(size_t)NQ * K_ + (size_t)q * K_ + lane] = n;                     // center_idx
    }
}

extern "C" void kernel_launch(void* const* d_in, const int* in_sizes, int n_in,
                              void* d_out, int out_size, void* d_ws, size_t ws_size,
                              hipStream_t stream) {
    const float* x = (const float*)d_in[0];
    int* out = (int*)d_out;
    char* ws = (char*)d_ws;
    float*          nrm    = (float*)ws;                          //  64 KB @ 0
    float*          tau    = (float*)(ws + (64 << 10));           //  64 KB
    unsigned short* cnt_pb = (unsigned short*)(ws + (128 << 10)); // 256 KB (16384*8*2)
    unsigned short* xh     = (unsigned short*)(ws + (1 << 20));   //   2 MB
    unsigned short* xl     = (unsigned short*)(ws + (3 << 20));   //   2 MB
    unsigned short* buf2   = (unsigned short*)(ws + (5 << 20));   // 10.5 MB (16384*8*40*2)
    float*          part   = (float*)(ws + (5 << 20));            //   8 MB, ALIASES buf2:
    // part is written by tau_p and fully consumed by tau_m BEFORE filter_k writes buf2.

    hipLaunchKernelGGL(split_k,  dim3(1024), dim3(256), 0, stream, x, xh, xl, nrm);
    hipLaunchKernelGGL(tau_p,    dim3(1024), dim3(256), 0, stream, xh, xl, nrm, part);
    hipLaunchKernelGGL(tau_m,    dim3(256),  dim3(64),  0, stream, part, tau);
    hipLaunchKernelGGL(filter_k, dim3(1024), dim3(256), 0, stream, xh, xl, nrm, tau, cnt_pb, buf2);
    hipLaunchKernelGGL(rerank_k, dim3(4096), dim3(256), 0, stream, x, cnt_pb, buf2, out);
}

// Round 14
// 249.285 us; speedup vs baseline: 1.0744x; 1.0744x over previous
//
#include <hip/hip_runtime.h>
#include <stdint.h>

// KNN K=16 over x (B=2, N=8192, D=64) f32. Output int32 (2,B,N,K): nn_idx, center_idx.
// Pipeline: split_k (bf16 hi + residual norms) -> red_k (batch maxima E=max||res||,
// Nmax) -> tau_p (MFMA hi-only min-ladders over 2048-sample) -> tau_m (merge ->
// per-query threshold with PROVABLE Cauchy-Schwarz slop) -> filter_k (MFMA hi-only
// distance, accept key <= tau) -> rerank_k (exact f64 on survivors).
// Bound: |key_approx - key_true| = 2|x_q.x_m - xh_q.xh_m| <= 2(n_q e_m + e_q h_m)
// <= 2(n_q E + e_q H) = s_q, with e_i MEASURED in split_k, H = Nmax + E. tau =
// u16_approx + 2 s_q (+6e-3 f32 fudge) provably keeps all true top-16; looser tau
// adds only ~2 survivors/query (rank-16 tail density ~1.5e-4/unit).
constexpr int N_    = 8192;
constexpr int D_    = 64;
constexpr int K_    = 16;
constexpr int NQ    = 16384;          // 2*8192
constexpr int MS    = 8;              // m-superblocks per batch (1024 m each)
constexpr int CAPB  = 40;             // survivor cap per (query, superblock): E~8.3, +11 sigma

typedef __attribute__((ext_vector_type(8))) short bf16x8;
typedef __attribute__((ext_vector_type(4))) float f32x4;

template<int JN>
__device__ __forceinline__ void topk_insertf(float (&key)[JN], float nk) {
    if (nk < key[JN - 1]) {
        bool c[JN];
#pragma unroll
        for (int j = 0; j < JN; ++j) c[j] = nk < key[j];
#pragma unroll
        for (int j = JN - 1; j >= 1; --j)
            key[j] = c[j - 1] ? key[j - 1] : (c[j] ? nk : key[j]);
        key[0] = c[0] ? nk : key[0];
    }
}

__device__ __forceinline__ unsigned short bf16_rne(float f) {
    uint32_t u = __float_as_uint(f);
    return (unsigned short)((u + 0x7FFFu + ((u >> 16) & 1u)) >> 16);   // no NaN in data
}

// async 16B global -> LDS (no VGPR round-trip). Dest = wave-uniform base + lane*16.
__device__ __forceinline__ void gl_lds16(const void* g, void* l) {
    __builtin_amdgcn_global_load_lds(
        (const __attribute__((address_space(1))) unsigned int*)g,
        (__attribute__((address_space(3))) unsigned int*)l, 16, 0, 0);
}

#define SWZ(r, s) (((r) << 7) + ((((s) ^ ((r) & 7))) << 4))

// K1: bf16 hi split + true squared norms + residual norms. 16 lanes/row. grid=1024.
__global__ void __launch_bounds__(256) split_k(const float* __restrict__ x,
                                               unsigned short* __restrict__ xh,
                                               float* __restrict__ nrm,
                                               float* __restrict__ eres) {
    const int t = blockIdx.x * 256 + (int)threadIdx.x;    // one float4 per thread
    const int row = t >> 4, seg = t & 15;
    const float4 v = reinterpret_cast<const float4*>(x)[t];
    float f[4] = {v.x, v.y, v.z, v.w};
    unsigned short h[4];
    float sq = 0.f, esq = 0.f;
#pragma unroll
    for (int j = 0; j < 4; ++j) {
        sq = fmaf(f[j], f[j], sq);
        h[j] = bf16_rne(f[j]);
        float hf = __uint_as_float((uint32_t)h[j] << 16);
        float r  = f[j] - hf;                             // exact (Sterbenz)
        esq = fmaf(r, r, esq);
    }
    sq  += __shfl_xor(sq, 1, 16);  sq  += __shfl_xor(sq, 2, 16);
    sq  += __shfl_xor(sq, 4, 16);  sq  += __shfl_xor(sq, 8, 16);
    esq += __shfl_xor(esq, 1, 16); esq += __shfl_xor(esq, 2, 16);
    esq += __shfl_xor(esq, 4, 16); esq += __shfl_xor(esq, 8, 16);
    if (seg == 0) { nrm[row] = sq; eres[row] = sqrtf(esq); }
    ushort4 hv = {h[0], h[1], h[2], h[3]};
    reinterpret_cast<ushort4*>(xh)[t] = hv;
}

// K1b: per-batch maxima: EH[b] = {Nmax, Emax} (inflated for f32 rounding).
// grid = 2 blocks (one per batch) x 256.
__global__ void __launch_bounds__(256) red_k(const float* __restrict__ nrm,
                                             const float* __restrict__ eres,
                                             float* __restrict__ EH) {
    __shared__ float mbuf[8];
    const int b = (int)blockIdx.x, tid = (int)threadIdx.x;
    float mn = 0.f, me = 0.f;
    for (int i = tid; i < N_; i += 256) {
        mn = fmaxf(mn, nrm[b * N_ + i]);
        me = fmaxf(me, eres[b * N_ + i]);
    }
#pragma unroll
    for (int s = 1; s < 64; s <<= 1) {
        mn = fmaxf(mn, __shfl_xor(mn, s, 64));
        me = fmaxf(me, __shfl_xor(me, s, 64));
    }
    const int w = tid >> 6;
    if ((tid & 63) == 0) { mbuf[w * 2] = mn; mbuf[w * 2 + 1] = me; }
    __syncthreads();
    if (tid == 0) {
        for (int i = 1; i < 4; ++i) {
            mn = fmaxf(mn, mbuf[i * 2]); me = fmaxf(me, mbuf[i * 2 + 1]);
        }
        EH[b * 2]     = sqrtf(mn) * 1.0002f + 1e-6f;      // Nmax (upper bound)
        EH[b * 2 + 1] = me * 1.0002f + 1e-7f;             // Emax (upper bound)
    }
}

// K2a: MFMA tau partials, hi-only. Block = 64 q x 512 samples (8 chunks of 64,
// DMA double-buffered). Depth-1 min ladder per (lane, q) -> 128 partials/query
// (subset of sample keys -> pigeonhole-valid). grid = 256 q-tiles x 4 quarters.
__global__ void __launch_bounds__(256, 4) tau_p(const unsigned short* __restrict__ xh,
                                                const float* __restrict__ nrm,
                                                float* __restrict__ part) {
    __shared__ alignas(16) unsigned short Bd[2][64 * 64];   // 2 x 8 KB (hi rows)
    __shared__ alignas(16) float nrmS[512];                 // 2 KB sample norms
    const int tid = (int)threadIdx.x;
    const int bid = (int)blockIdx.x;
    const int qb  = bid >> 2, sh = bid & 3;                 // q-tile, sample-quarter
    const int q0g = qb * 64;
    const int b   = q0g >> 13;                              // uniform (64 | 8192)
    const int q0l = q0g & (N_ - 1);
    const int s0  = sh * 512;                               // sample base within batch
    const unsigned short* __restrict__ xhb = xh + (size_t)b * N_ * D_;
    const float* __restrict__ nb = nrm + b * N_;
    const int w = tid >> 6, lane = tid & 63;
    const int wq = w >> 1, wm = w & 1;                      // 32q x 32m wave subtile
    const int l15 = lane & 15, quad = lane >> 4;

    bf16x8 Af[2][2];                                        // A frags from global (hi)
#pragma unroll
    for (int half = 0; half < 2; ++half) {
        const int ko = (half * 4 + quad) << 4;
#pragma unroll
        for (int tm = 0; tm < 2; ++tm) {
            const int r = q0l + wq * 32 + tm * 16 + l15;
            Af[half][tm] = *(const bf16x8*)((const char*)(xhb + (size_t)r * D_) + ko);
        }
    }
    {                                                       // async stage chunk 0
#pragma unroll
        for (int k = 0; k < 2; ++k) {
            int u = k * 256 + tid, r = u >> 3, sg = (u & 7) ^ (r & 7);
            gl_lds16((const char*)(xhb + (size_t)(s0 + r) * D_) + (sg << 4),
                     (char*)Bd[0] + (k << 12) + (w << 10));
        }
    }
    *(float2*)(nrmS + tid * 2) = *(const float2*)(nb + s0 + tid * 2);

    float lad[8];
#pragma unroll
    for (int j = 0; j < 8; ++j) lad[j] = __builtin_inff();
    __syncthreads();                                        // chunk 0 + nrmS visible

    for (int mc = 0; mc < 8; ++mc) {
        const int cur = mc & 1;
        if (mc < 7) {                                       // async stage next chunk
            const int m0n = s0 + (mc + 1) * 64;
#pragma unroll
            for (int k = 0; k < 2; ++k) {
                int u = k * 256 + tid, r = u >> 3, sg = (u & 7) ^ (r & 7);
                gl_lds16((const char*)(xhb + (size_t)(m0n + r) * D_) + (sg << 4),
                         (char*)Bd[1 - cur] + (k << 12) + (w << 10));
            }
        }
        f32x4 acc[2][2] = {};
#pragma unroll
        for (int half = 0; half < 2; ++half) {
            const int seg = half * 4 + quad;
            bf16x8 bf[2];
#pragma unroll
            for (int tn = 0; tn < 2; ++tn)
                bf[tn] = *(const bf16x8*)((const char*)Bd[cur] + SWZ(wm * 32 + tn * 16 + l15, seg));
#pragma unroll
            for (int tm = 0; tm < 2; ++tm)
#pragma unroll
                for (int tn = 0; tn < 2; ++tn)
                    acc[tm][tn] = __builtin_amdgcn_mfma_f32_16x16x32_bf16(Af[half][tm], bf[tn], acc[tm][tn], 0, 0, 0);
        }
        // epilogue: C/D col=lane&15 (m), row=quad*4+reg (q); depth-1 min ladder
#pragma unroll
        for (int tn = 0; tn < 2; ++tn) {
            const float nm = nrmS[mc * 64 + wm * 32 + tn * 16 + l15];
#pragma unroll
            for (int tm = 0; tm < 2; ++tm)
#pragma unroll
                for (int reg = 0; reg < 4; ++reg)
                    lad[tm * 4 + reg] = fminf(lad[tm * 4 + reg],
                                              fmaf(-2.f, acc[tm][tn][reg], nm));
        }
        __syncthreads();                                    // seals Bd[cur] + DMA drain
    }
#pragma unroll
    for (int tm = 0; tm < 2; ++tm)
#pragma unroll
        for (int reg = 0; reg < 4; ++reg) {
            const int q = q0g + wq * 32 + tm * 16 + quad * 4 + reg;
            part[(size_t)q * 128 + sh * 32 + wm * 16 + l15] = lad[tm * 4 + reg];
        }
}

// K2b: merge 128 partials/query -> tau with provable slop. grid = NQ/64 = 256.
__global__ void __launch_bounds__(64) tau_m(const float* __restrict__ part,
                                            const float* __restrict__ nrm,
                                            const float* __restrict__ eres,
                                            const float* __restrict__ EH,
                                            float* __restrict__ tau) {
    const int q = blockIdx.x * 64 + (int)threadIdx.x;
    const int b = q >> 13;
    const float4* p = reinterpret_cast<const float4*>(part + (size_t)q * 128);
    float key[K_];
#pragma unroll
    for (int j = 0; j < K_; ++j) key[j] = __builtin_inff();
    for (int i = 0; i < 32; ++i) {
        float4 v = p[i];
        topk_insertf<K_>(key, v.x); topk_insertf<K_>(key, v.y);
        topk_insertf<K_>(key, v.z); topk_insertf<K_>(key, v.w);
    }
    const float Nmax = EH[b * 2], Emax = EH[b * 2 + 1];
    const float H = Nmax + Emax;                            // >= max ||xh_m||
    const float nq = sqrtf(nrm[q]) * 1.0001f, eq = eres[q];
    // tau = u16_approx + 2*s_q, s_q = 2(n_q E + e_q H); +6e-3 covers f32 accum
    tau[q] = key[15] + 4.f * (nq * Emax + eq * H) + 6e-3f;
}

// K3: MFMA filter, hi-only. Block = 128q x 1024m, 16 chunks of 64m, double-buffered
// async staging, A (hi, 16 KB) staged once -> VGPR frags. Accepts via LDS atomics
// (measured-best epilogue, R12). 46.5 KB LDS -> 3 blocks/CU. grid = 1024 x 256.
__global__ void __launch_bounds__(256, 3) filter_k(const unsigned short* __restrict__ xh,
                                                   const float* __restrict__ nrm,
                                                   const float* __restrict__ tau,
                                                   unsigned short* __restrict__ cnt_pb,
                                                   unsigned short* __restrict__ buf2) {
    __shared__ alignas(16) unsigned short A[128 * 64];      // 16 KB q rows (hi)
    __shared__ alignas(16) unsigned short Bd[2][64 * 64];   // 2 x 8 KB m rows (hi)
    __shared__ alignas(16) float nrmS[1024];                // 4 KB superblock norms
    __shared__ unsigned short lists[128 * CAPB];            // 10 KB
    __shared__ unsigned int cntL[128];
    const int tid = (int)threadIdx.x;
    const int bid = (int)blockIdx.x;
    const int b  = bid >> 9;
    const int qt = (bid >> 3) & 63;
    const int ms = bid & 7;
    const int q0 = qt * 128;
    const unsigned short* __restrict__ xhb = xh + (size_t)b * N_ * D_;
    const float* __restrict__ nb = nrm + b * N_;
    const int w = tid >> 6, lane = tid & 63;
    const int wq = w >> 1, wm = w & 1;                      // 64q x 32m wave subtile
    const int l15 = lane & 15, quad = lane >> 4;

#pragma unroll
    for (int k = 0; k < 4; ++k) {                           // async stage A (16 KB)
        int u = k * 256 + tid, r = u >> 3, sg = (u & 7) ^ (r & 7);
        gl_lds16((const char*)(xhb + (size_t)(q0 + r) * D_) + (sg << 4),
                 (char*)A + (k << 12) + (w << 10));
    }
    {                                                       // async stage B chunk 0
        const int m0 = ms * 1024;
#pragma unroll
        for (int k = 0; k < 2; ++k) {
            int u = k * 256 + tid, r = u >> 3, sg = (u & 7) ^ (r & 7);
            gl_lds16((const char*)(xhb + (size_t)(m0 + r) * D_) + (sg << 4),
                     (char*)Bd[0] + (k << 12) + (w << 10));
        }
    }
    *(float4*)(nrmS + tid * 4) = *(const float4*)(nb + ms * 1024 + tid * 4);
    if (tid < 128) cntL[tid] = 0;
    f32x4 t4v[4];                                           // thresholds straight to VGPRs
#pragma unroll
    for (int tm = 0; tm < 4; ++tm)
        t4v[tm] = *(const f32x4*)(tau + (b << 13) + q0 + wq * 64 + tm * 16 + quad * 4);
    __syncthreads();                                        // A + chunk0 + nrmS visible

    bf16x8 Af[2][4];                                        // A frags (chunk-invariant)
#pragma unroll
    for (int half = 0; half < 2; ++half) {
        const int seg = half * 4 + quad;
#pragma unroll
        for (int tm = 0; tm < 4; ++tm)
            Af[half][tm] = *(const bf16x8*)((const char*)A + SWZ(wq * 64 + tm * 16 + l15, seg));
    }

    for (int mc = 0; mc < 16; ++mc) {
        const int cur = mc & 1;
        if (mc < 15) {                                      // async stage next chunk
            const int m0n = ms * 1024 + (mc + 1) * 64;
#pragma unroll
            for (int k = 0; k < 2; ++k) {
                int u = k * 256 + tid, r = u >> 3, sg = (u & 7) ^ (r & 7);
                gl_lds16((const char*)(xhb + (size_t)(m0n + r) * D_) + (sg << 4),
                         (char*)Bd[1 - cur] + (k << 12) + (w << 10));
            }
        }
        f32x4 acc[4][2] = {};
#pragma unroll
        for (int half = 0; half < 2; ++half) {
            const int seg = half * 4 + quad;
            bf16x8 bf[2];
#pragma unroll
            for (int tn = 0; tn < 2; ++tn)
                bf[tn] = *(const bf16x8*)((const char*)Bd[cur] + SWZ(wm * 32 + tn * 16 + l15, seg));
#pragma unroll
            for (int tm = 0; tm < 4; ++tm)
#pragma unroll
                for (int tn = 0; tn < 2; ++tn)
                    acc[tm][tn] = __builtin_amdgcn_mfma_f32_16x16x32_bf16(Af[half][tm], bf[tn], acc[tm][tn], 0, 0, 0);
        }
        // epilogue: C/D col=lane&15 (m), row=quad*4+reg (q); accept key <= tau
#pragma unroll
        for (int tn = 0; tn < 2; ++tn) {
            const int mloc = wm * 32 + tn * 16 + l15;
            const float nm = nrmS[mc * 64 + mloc];
            const unsigned short mid = (unsigned short)(ms * 1024 + mc * 64 + mloc);
#pragma unroll
            for (int tm = 0; tm < 4; ++tm)
#pragma unroll
                for (int reg = 0; reg < 4; ++reg) {
                    float keyf = fmaf(-2.f, acc[tm][tn][reg], nm);
                    if (keyf <= t4v[tm][reg]) {             // rare (~0.8%)
                        int ql = wq * 64 + tm * 16 + quad * 4 + reg;
                        unsigned pos = atomicAdd(&cntL[ql], 1u);    // LDS atomic
                        if (pos < CAPB) lists[ql * CAPB + pos] = mid;
                    }
                }
        }
        __syncthreads();                                    // seals Bd[cur] + DMA drain
    }
    if (tid < 128) {                                        // flush to fixed slots
        const int q = (b << 13) + q0 + tid;
        unsigned cn = cntL[tid]; cn = cn < CAPB ? cn : CAPB;
        cnt_pb[(size_t)q * MS + ms] = (unsigned short)cn;
        unsigned short* dst = buf2 + ((size_t)q * MS + ms) * CAPB;
        for (unsigned i = 0; i < cn; ++i) dst[i] = lists[tid * CAPB + i];
    }
}

// K4: exact f64 rerank, wave-per-query. Each lane computes one candidate's full
// 64-dim f64 distance (gather loads + LDS-broadcast Q); selection via 64-lane
// bitonic sort of packed u64 (dist,id) keys: keep top-16 in lanes 0-15, refill
// 48, resort. block 256 = 4 waves = 4 queries; grid = NQ/4 = 4096.
__global__ void __launch_bounds__(256) rerank_k(const float* __restrict__ x,
                                                const unsigned short* __restrict__ cnt_pb,
                                                const unsigned short* __restrict__ buf2,
                                                int* __restrict__ out) {
    __shared__ float Qs[4 * 64];                           // 1 KB query rows
    __shared__ unsigned short ids[4 * MS * CAPB];          // 2.5 KB compacted survivors
    const int tid = (int)threadIdx.x;
    const int w = tid >> 6, lane = tid & 63;
    const int q = blockIdx.x * 4 + w;
    const int b = q >> 13, n = q & (N_ - 1);
    const float* __restrict__ xb = x + (size_t)b * N_ * D_;
    Qs[w * 64 + lane] = xb[(size_t)n * D_ + lane];

    int off[MS + 1]; off[0] = 0;                           // all lanes compute same
#pragma unroll
    for (int ms = 0; ms < MS; ++ms) {
        int c = (int)cnt_pb[(size_t)q * MS + ms]; c = c < CAPB ? c : CAPB;
        off[ms + 1] = off[ms] + c;
    }
    const int total = off[MS];                             // >= 16 guaranteed (true top-16 pass)
    for (int idx = lane; idx < total; idx += 64) {         // compact ids into LDS
        int ms = 0;
#pragma unroll
        for (int t = 1; t < MS; ++t) ms += (idx >= off[t]) ? 1 : 0;
        ids[(w * MS) * CAPB + idx] = buf2[((size_t)q * MS + ms) * CAPB + (idx - off[ms])];
    }
    __syncthreads();

    unsigned long long v = ~0ull;
    int consumed = 0;
    bool first = true;
    while (first || consumed < total) {
        const int myIdx = first ? lane : consumed + lane - 16;
        const bool take = (first || lane >= 16) && myIdx < total;
        unsigned long long nk = ~0ull;
        if (take) {
            const int id = (int)ids[(w * MS) * CAPB + myIdx];
            const float* __restrict__ crow = xb + (size_t)id * D_;
            double a0 = 0.0, a1 = 0.0, a2 = 0.0, a3 = 0.0;
#pragma unroll
            for (int j = 0; j < 16; ++j) {
                const float4 c  = *(const float4*)(crow + j * 4);        // per-lane gather
                const float4 qv = *(const float4*)(Qs + w * 64 + j * 4); // uniform -> broadcast
                double d0 = (double)qv.x - (double)c.x; a0 = fma(d0, d0, a0);
                double d1 = (double)qv.y - (double)c.y; a1 = fma(d1, d1, a1);
                double d2 = (double)qv.z - (double)c.z; a2 = fma(d2, d2, a2);
                double d3 = (double)qv.w - (double)c.w; a3 = fma(d3, d3, a3);
            }
            double s = (a0 + a1) + (a2 + a3);
            // s >= 0 -> f64 bits order-preserving; low 13 mantissa bits carry the id
            // for exact (dist, id) lexicographic compare (ties -> lower id).
            nk = ((unsigned long long)__double_as_longlong(s) & ~0x1FFFull) | (unsigned)id;
        }
        if (first || lane >= 16) v = nk;                   // lanes 0-15 keep running top-16
        // 64-lane bitonic sort ascending (21 steps)
#pragma unroll
        for (int k = 2; k <= 64; k <<= 1)
#pragma unroll
            for (int j = k >> 1; j > 0; j >>= 1) {
                unsigned long long o = __shfl_xor(v, j, 64);
                const bool keepmin = (((lane & k) == 0) == ((lane & j) == 0));
                unsigned long long mn = v < o ? v : o;
                unsigned long long mx = v < o ? o : v;
                v = keepmin ? mn : mx;
            }
        consumed += first ? 64 : 48;
        first = false;
    }
    if (lane < K_) {
        out[(size_t)q * K_ + lane]                   = (int)(v & 0x1FFFull);  // nn_idx
        out[(size_t)NQ * K_ + (size_t)q * K_ + lane] = n;                     // center_idx
    }
}

extern "C" void kernel_launch(void* const* d_in, const int* in_sizes, int n_in,
                              void* d_out, int out_size, void* d_ws, size_t ws_size,
                              hipStream_t stream) {
    const float* x = (const float*)d_in[0];
    int* out = (int*)d_out;
    char* ws = (char*)d_ws;
    float*          nrm    = (float*)ws;                          //  64 KB @ 0
    float*          tau    = (float*)(ws + (64 << 10));           //  64 KB
    float*          eres   = (float*)(ws + (128 << 10));          //  64 KB
    float*          EH     = (float*)(ws + (192 << 10));          //  16 B
    unsigned short* cnt_pb = (unsigned short*)(ws + (256 << 10)); // 256 KB
    unsigned short* xh     = (unsigned short*)(ws + (1 << 20));   //   2 MB
    unsigned short* buf2   = (unsigned short*)(ws + (5 << 20));   // 10.5 MB (16384*8*40*2)
    float*          part   = (float*)(ws + (5 << 20));            //   8 MB, ALIASES buf2:
    // part is written by tau_p and fully consumed by tau_m BEFORE filter_k writes buf2.

    hipLaunchKernelGGL(split_k,  dim3(1024), dim3(256), 0, stream, x, xh, nrm, eres);
    hipLaunchKernelGGL(red_k,    dim3(2),    dim3(256), 0, stream, nrm, eres, EH);
    hipLaunchKernelGGL(tau_p,    dim3(1024), dim3(256), 0, stream, xh, nrm, part);
    hipLaunchKernelGGL(tau_m,    dim3(256),  dim3(64),  0, stream, part, nrm, eres, EH, tau);
    hipLaunchKernelGGL(filter_k, dim3(1024), dim3(256), 0, stream, xh, nrm, tau, cnt_pb, buf2);
    hipLaunchKernelGGL(rerank_k, dim3(4096), dim3(256), 0, stream, x, cnt_pb, buf2, out);
}

// Round 15
// 208.457 us; speedup vs baseline: 1.2849x; 1.1959x over previous
//
#include <hip/hip_runtime.h>
#include <stdint.h>

// KNN K=16 over x (B=2, N=8192, D=64) f32. Output int32 (2,B,N,K): nn_idx, center_idx.
// Pipeline: split_k (bf16 hi + residual norms) -> red_k (batch maxima) -> tau_p
// (MFMA hi-only min-ladders over 2048-sample, barrier-free streaming) -> tau_m
// (merge -> per-query threshold with PROVABLE Cauchy-Schwarz slop) -> filter_k
// (MFMA hi-only distance, BARRIER-FREE: A/B fragments gathered from L2-resident
// xh, no LDS staging, accepts via LDS atomics) -> rerank_k (exact f64).
// Bound: |key_approx - key_true| <= 2(n_q E + e_q H) with e_i MEASURED in split_k,
// E = max e, H = Nmax + E. tau = u16_approx + 2*slop provably keeps all true
// top-16 (pigeonhole over the 2048-sample for u16 >= true d16).
constexpr int N_    = 8192;
constexpr int D_    = 64;
constexpr int K_    = 16;
constexpr int NQ    = 16384;          // 2*8192
constexpr int MS    = 8;              // m-superblocks per batch (1024 m each)
constexpr int CAPB  = 40;             // survivor cap per (query, superblock)

typedef __attribute__((ext_vector_type(8))) short bf16x8;
typedef __attribute__((ext_vector_type(4))) float f32x4;

template<int JN>
__device__ __forceinline__ void topk_insertf(float (&key)[JN], float nk) {
    if (nk < key[JN - 1]) {
        bool c[JN];
#pragma unroll
        for (int j = 0; j < JN; ++j) c[j] = nk < key[j];
#pragma unroll
        for (int j = JN - 1; j >= 1; --j)
            key[j] = c[j - 1] ? key[j - 1] : (c[j] ? nk : key[j]);
        key[0] = c[0] ? nk : key[0];
    }
}

__device__ __forceinline__ unsigned short bf16_rne(float f) {
    uint32_t u = __float_as_uint(f);
    return (unsigned short)((u + 0x7FFFu + ((u >> 16) & 1u)) >> 16);   // no NaN in data
}

// K1: bf16 hi split + true squared norms + residual norms. 16 lanes/row. grid=1024.
__global__ void __launch_bounds__(256) split_k(const float* __restrict__ x,
                                               unsigned short* __restrict__ xh,
                                               float* __restrict__ nrm,
                                               float* __restrict__ eres) {
    const int t = blockIdx.x * 256 + (int)threadIdx.x;    // one float4 per thread
    const int row = t >> 4, seg = t & 15;
    const float4 v = reinterpret_cast<const float4*>(x)[t];
    float f[4] = {v.x, v.y, v.z, v.w};
    unsigned short h[4];
    float sq = 0.f, esq = 0.f;
#pragma unroll
    for (int j = 0; j < 4; ++j) {
        sq = fmaf(f[j], f[j], sq);
        h[j] = bf16_rne(f[j]);
        float hf = __uint_as_float((uint32_t)h[j] << 16);
        float r  = f[j] - hf;
        esq = fmaf(r, r, esq);
    }
    sq  += __shfl_xor(sq, 1, 16);  sq  += __shfl_xor(sq, 2, 16);
    sq  += __shfl_xor(sq, 4, 16);  sq  += __shfl_xor(sq, 8, 16);
    esq += __shfl_xor(esq, 1, 16); esq += __shfl_xor(esq, 2, 16);
    esq += __shfl_xor(esq, 4, 16); esq += __shfl_xor(esq, 8, 16);
    if (seg == 0) { nrm[row] = sq; eres[row] = sqrtf(esq); }
    ushort4 hv = {h[0], h[1], h[2], h[3]};
    reinterpret_cast<ushort4*>(xh)[t] = hv;
}

// K1b: per-batch maxima: EH[b] = {Nmax, Emax} (inflated for f32 rounding). grid=2.
__global__ void __launch_bounds__(256) red_k(const float* __restrict__ nrm,
                                             const float* __restrict__ eres,
                                             float* __restrict__ EH) {
    __shared__ float mbuf[8];
    const int b = (int)blockIdx.x, tid = (int)threadIdx.x;
    float mn = 0.f, me = 0.f;
    for (int i = tid; i < N_; i += 256) {
        mn = fmaxf(mn, nrm[b * N_ + i]);
        me = fmaxf(me, eres[b * N_ + i]);
    }
#pragma unroll
    for (int s = 1; s < 64; s <<= 1) {
        mn = fmaxf(mn, __shfl_xor(mn, s, 64));
        me = fmaxf(me, __shfl_xor(me, s, 64));
    }
    const int w = tid >> 6;
    if ((tid & 63) == 0) { mbuf[w * 2] = mn; mbuf[w * 2 + 1] = me; }
    __syncthreads();
    if (tid == 0) {
        for (int i = 1; i < 4; ++i) {
            mn = fmaxf(mn, mbuf[i * 2]); me = fmaxf(me, mbuf[i * 2 + 1]);
        }
        EH[b * 2]     = sqrtf(mn) * 1.0002f + 1e-6f;      // Nmax upper bound
        EH[b * 2 + 1] = me * 1.0002f + 1e-7f;             // Emax upper bound
    }
}

// K2a: MFMA tau partials, barrier-free streaming (filter template). Block =
// 128q x 512 samples (quarter sh of the 2048-sample), 8 chunks of 64; A/B frags
// gathered from global (L2). Depth-1 min ladder -> 128 partials/query.
// grid = 128 q-tiles x 4 quarters = 512 blocks of 256.
__global__ void __launch_bounds__(256, 4) tau_p(const unsigned short* __restrict__ xh,
                                                const float* __restrict__ nrm,
                                                float* __restrict__ part) {
    __shared__ alignas(16) float nrmS[512];                 // 2 KB sample norms
    const int tid = (int)threadIdx.x;
    const int bid = (int)blockIdx.x;
    const int qt  = bid >> 2, sh = bid & 3;
    const int q0g = qt * 128;
    const int b   = q0g >> 13;                              // uniform (128 | 8192)
    const int q0l = q0g & (N_ - 1);
    const int s0  = sh * 512;
    const unsigned short* __restrict__ xhb = xh + (size_t)b * N_ * D_;
    const float* __restrict__ nb = nrm + b * N_;
    const int w = tid >> 6, lane = tid & 63;
    const int wq = w >> 1, wm = w & 1;                      // 64q x 32s wave subtile
    const int l15 = lane & 15, quad = lane >> 4;

    if (tid < 128) *(float4*)(nrmS + tid * 4) = *(const float4*)(nb + s0 + tid * 4);

    bf16x8 Af[2][4];                                        // A frags from global
#pragma unroll
    for (int half = 0; half < 2; ++half) {
        const int eo = (half * 4 + quad) * 8;               // element offset in row
#pragma unroll
        for (int tm = 0; tm < 4; ++tm)
            Af[half][tm] = *(const bf16x8*)(xhb + (size_t)(q0l + wq * 64 + tm * 16 + l15) * D_ + eo);
    }
    float lad[16];
#pragma unroll
    for (int j = 0; j < 16; ++j) lad[j] = __builtin_inff();
    __syncthreads();                                        // nrmS visible

    for (int mc = 0; mc < 8; ++mc) {
        const unsigned short* Bbase = xhb + (size_t)(s0 + mc * 64) * D_;
        bf16x8 Bf[2][2];                                    // B frags from global (coalesced lines)
#pragma unroll
        for (int half = 0; half < 2; ++half) {
            const int eo = (half * 4 + quad) * 8;
#pragma unroll
            for (int tn = 0; tn < 2; ++tn)
                Bf[half][tn] = *(const bf16x8*)(Bbase + (size_t)(wm * 32 + tn * 16 + l15) * D_ + eo);
        }
        f32x4 acc[4][2] = {};
#pragma unroll
        for (int half = 0; half < 2; ++half)
#pragma unroll
            for (int tm = 0; tm < 4; ++tm)
#pragma unroll
                for (int tn = 0; tn < 2; ++tn)
                    acc[tm][tn] = __builtin_amdgcn_mfma_f32_16x16x32_bf16(Af[half][tm], Bf[half][tn], acc[tm][tn], 0, 0, 0);
        // epilogue: C/D col=lane&15 (sample), row=quad*4+reg (q); depth-1 min
#pragma unroll
        for (int tn = 0; tn < 2; ++tn) {
            const float nm = nrmS[mc * 64 + wm * 32 + tn * 16 + l15];
#pragma unroll
            for (int tm = 0; tm < 4; ++tm)
#pragma unroll
                for (int reg = 0; reg < 4; ++reg)
                    lad[tm * 4 + reg] = fminf(lad[tm * 4 + reg],
                                              fmaf(-2.f, acc[tm][tn][reg], nm));
        }
    }
    // part[q][128]: offset = sh*32 + wm*16 + l15
#pragma unroll
    for (int tm = 0; tm < 4; ++tm)
#pragma unroll
        for (int reg = 0; reg < 4; ++reg) {
            const int q = q0g + wq * 64 + tm * 16 + quad * 4 + reg;
            part[(size_t)q * 128 + sh * 32 + wm * 16 + l15] = lad[tm * 4 + reg];
        }
}

// K2b: merge 128 partials/query -> tau with provable slop. grid = NQ/64 = 256.
__global__ void __launch_bounds__(64) tau_m(const float* __restrict__ part,
                                            const float* __restrict__ nrm,
                                            const float* __restrict__ eres,
                                            const float* __restrict__ EH,
                                            float* __restrict__ tau) {
    const int q = blockIdx.x * 64 + (int)threadIdx.x;
    const int b = q >> 13;
    const float4* p = reinterpret_cast<const float4*>(part + (size_t)q * 128);
    float key[K_];
#pragma unroll
    for (int j = 0; j < K_; ++j) key[j] = __builtin_inff();
    for (int i = 0; i < 32; ++i) {
        float4 v = p[i];
        topk_insertf<K_>(key, v.x); topk_insertf<K_>(key, v.y);
        topk_insertf<K_>(key, v.z); topk_insertf<K_>(key, v.w);
    }
    const float Nmax = EH[b * 2], Emax = EH[b * 2 + 1];
    const float H = Nmax + Emax;                            // >= max ||xh_m||
    const float nq = sqrtf(nrm[q]) * 1.0001f, eq = eres[q];
    tau[q] = key[15] + 4.f * (nq * Emax + eq * H) + 6e-3f;  // 2*s_q + f32 fudge
}

// K3: MFMA filter, BARRIER-FREE streaming. Block = 128q x 1024m, 16 chunks of
// 64m. A/B fragments gathered straight from L2-resident xh (wave's B load for
// one (half,tn) = 16 rows x one full 64-B line -> ideal line count). No LDS
// staging, no per-chunk barriers -> compiler interleaves next-chunk loads with
// MFMA/epilogue; 4 blocks/CU (LDS 14.8 KB, VGPR ~116) overlap the rest.
// Accepts -> LDS per-query lists (DS atomics). grid = 2*64*8 = 1024 blocks.
__global__ void __launch_bounds__(256, 4) filter_k(const unsigned short* __restrict__ xh,
                                                   const float* __restrict__ nrm,
                                                   const float* __restrict__ tau,
                                                   unsigned short* __restrict__ cnt_pb,
                                                   unsigned short* __restrict__ buf2) {
    __shared__ alignas(16) float nrmS[1024];                // 4 KB superblock norms
    __shared__ unsigned short lists[128 * CAPB];            // 10 KB
    __shared__ unsigned int cntL[128];
    const int tid = (int)threadIdx.x;
    const int bid = (int)blockIdx.x;
    const int b  = bid >> 9;
    const int qt = (bid >> 3) & 63;
    const int ms = bid & 7;
    const int q0 = qt * 128;
    const unsigned short* __restrict__ xhb = xh + (size_t)b * N_ * D_;
    const float* __restrict__ nb = nrm + b * N_;
    const int w = tid >> 6, lane = tid & 63;
    const int wq = w >> 1, wm = w & 1;                      // 64q x 32m wave subtile
    const int l15 = lane & 15, quad = lane >> 4;

    *(float4*)(nrmS + tid * 4) = *(const float4*)(nb + ms * 1024 + tid * 4);
    if (tid < 128) cntL[tid] = 0;

    bf16x8 Af[2][4];                                        // A frags from global
#pragma unroll
    for (int half = 0; half < 2; ++half) {
        const int eo = (half * 4 + quad) * 8;
#pragma unroll
        for (int tm = 0; tm < 4; ++tm)
            Af[half][tm] = *(const bf16x8*)(xhb + (size_t)(q0 + wq * 64 + tm * 16 + l15) * D_ + eo);
    }
    f32x4 t4v[4];
#pragma unroll
    for (int tm = 0; tm < 4; ++tm)
        t4v[tm] = *(const f32x4*)(tau + (b << 13) + q0 + wq * 64 + tm * 16 + quad * 4);
    __syncthreads();                                        // nrmS visible

    for (int mc = 0; mc < 16; ++mc) {
        const unsigned short* Bbase = xhb + (size_t)(ms * 1024 + mc * 64) * D_;
        bf16x8 Bf[2][2];                                    // coalesced line gathers
#pragma unroll
        for (int half = 0; half < 2; ++half) {
            const int eo = (half * 4 + quad) * 8;
#pragma unroll
            for (int tn = 0; tn < 2; ++tn)
                Bf[half][tn] = *(const bf16x8*)(Bbase + (size_t)(wm * 32 + tn * 16 + l15) * D_ + eo);
        }
        f32x4 acc[4][2] = {};
#pragma unroll
        for (int half = 0; half < 2; ++half)
#pragma unroll
            for (int tm = 0; tm < 4; ++tm)
#pragma unroll
                for (int tn = 0; tn < 2; ++tn)
                    acc[tm][tn] = __builtin_amdgcn_mfma_f32_16x16x32_bf16(Af[half][tm], Bf[half][tn], acc[tm][tn], 0, 0, 0);
        // epilogue: C/D col=lane&15 (m), row=quad*4+reg (q); accept key <= tau
#pragma unroll
        for (int tn = 0; tn < 2; ++tn) {
            const int mloc = mc * 64 + wm * 32 + tn * 16 + l15;
            const float nm = nrmS[mloc];
            const unsigned short mid = (unsigned short)(ms * 1024 + mloc);
#pragma unroll
            for (int tm = 0; tm < 4; ++tm)
#pragma unroll
                for (int reg = 0; reg < 4; ++reg) {
                    float keyf = fmaf(-2.f, acc[tm][tn][reg], nm);
                    if (keyf <= t4v[tm][reg]) {             // rare (~0.8%)
                        int ql = wq * 64 + tm * 16 + quad * 4 + reg;
                        unsigned pos = atomicAdd(&cntL[ql], 1u);    // LDS atomic
                        if (pos < CAPB) lists[ql * CAPB + pos] = mid;
                    }
                }
        }
    }
    __syncthreads();                                        // all waves' accepts visible
    if (tid < 128) {                                        // flush to fixed slots
        const int q = (b << 13) + q0 + tid;
        unsigned cn = cntL[tid]; cn = cn < CAPB ? cn : CAPB;
        cnt_pb[(size_t)q * MS + ms] = (unsigned short)cn;
        unsigned short* dst = buf2 + ((size_t)q * MS + ms) * CAPB;
        for (unsigned i = 0; i < cn; ++i) dst[i] = lists[tid * CAPB + i];
    }
}

// K4: exact f64 rerank, wave-per-query. Each lane computes one candidate's full
// 64-dim f64 distance (gather loads + LDS-broadcast Q); selection via 64-lane
// bitonic sort of packed u64 (dist,id) keys: keep top-16 in lanes 0-15, refill
// 48, resort. block 256 = 4 waves = 4 queries; grid = NQ/4 = 4096.
__global__ void __launch_bounds__(256) rerank_k(const float* __restrict__ x,
                                                const unsigned short* __restrict__ cnt_pb,
                                                const unsigned short* __restrict__ buf2,
                                                int* __restrict__ out) {
    __shared__ float Qs[4 * 64];                           // 1 KB query rows
    __shared__ unsigned short ids[4 * MS * CAPB];          // 2.5 KB compacted survivors
    const int tid = (int)threadIdx.x;
    const int w = tid >> 6, lane = tid & 63;
    const int q = blockIdx.x * 4 + w;
    const int b = q >> 13, n = q & (N_ - 1);
    const float* __restrict__ xb = x + (size_t)b * N_ * D_;
    Qs[w * 64 + lane] = xb[(size_t)n * D_ + lane];

    int off[MS + 1]; off[0] = 0;                           // all lanes compute same
#pragma unroll
    for (int ms = 0; ms < MS; ++ms) {
        int c = (int)cnt_pb[(size_t)q * MS + ms]; c = c < CAPB ? c : CAPB;
        off[ms + 1] = off[ms] + c;
    }
    const int total = off[MS];                             // >= 16 guaranteed (true top-16 pass)
    for (int idx = lane; idx < total; idx += 64) {         // compact ids into LDS
        int ms = 0;
#pragma unroll
        for (int t = 1; t < MS; ++t) ms += (idx >= off[t]) ? 1 : 0;
        ids[(w * MS) * CAPB + idx] = buf2[((size_t)q * MS + ms) * CAPB + (idx - off[ms])];
    }
    __syncthreads();

    unsigned long long v = ~0ull;
    int consumed = 0;
    bool first = true;
    while (first || consumed < total) {
        const int myIdx = first ? lane : consumed + lane - 16;
        const bool take = (first || lane >= 16) && myIdx < total;
        unsigned long long nk = ~0ull;
        if (take) {
            const int id = (int)ids[(w * MS) * CAPB + myIdx];
            const float* __restrict__ crow = xb + (size_t)id * D_;
            double a0 = 0.0, a1 = 0.0, a2 = 0.0, a3 = 0.0;
#pragma unroll
            for (int j = 0; j < 16; ++j) {
                const float4 c  = *(const float4*)(crow + j * 4);        // per-lane gather
                const float4 qv = *(const float4*)(Qs + w * 64 + j * 4); // uniform -> broadcast
                double d0 = (double)qv.x - (double)c.x; a0 = fma(d0, d0, a0);
                double d1 = (double)qv.y - (double)c.y; a1 = fma(d1, d1, a1);
                double d2 = (double)qv.z - (double)c.z; a2 = fma(d2, d2, a2);
                double d3 = (double)qv.w - (double)c.w; a3 = fma(d3, d3, a3);
            }
            double s = (a0 + a1) + (a2 + a3);
            // s >= 0 -> f64 bits order-preserving; low 13 mantissa bits carry the id
            // for exact (dist, id) lexicographic compare (ties -> lower id).
            nk = ((unsigned long long)__double_as_longlong(s) & ~0x1FFFull) | (unsigned)id;
        }
        if (first || lane >= 16) v = nk;                   // lanes 0-15 keep running top-16
        // 64-lane bitonic sort ascending (21 steps)
#pragma unroll
        for (int k = 2; k <= 64; k <<= 1)
#pragma unroll
            for (int j = k >> 1; j > 0; j >>= 1) {
                unsigned long long o = __shfl_xor(v, j, 64);
                const bool keepmin = (((lane & k) == 0) == ((lane & j) == 0));
                unsigned long long mn = v < o ? v : o;
                unsigned long long mx = v < o ? o : v;
                v = keepmin ? mn : mx;
            }
        consumed += first ? 64 : 48;
        first = false;
    }
    if (lane < K_) {
        out[(size_t)q * K_ + lane]                   = (int)(v & 0x1FFFull);  // nn_idx
        out[(size_t)NQ * K_ + (size_t)q * K_ + lane] = n;                     // center_idx
    }
}

extern "C" void kernel_launch(void* const* d_in, const int* in_sizes, int n_in,
                              void* d_out, int out_size, void* d_ws, size_t ws_size,
                              hipStream_t stream) {
    const float* x = (const float*)d_in[0];
    int* out = (int*)d_out;
    char* ws = (char*)d_ws;
    float*          nrm    = (float*)ws;                          //  64 KB @ 0
    float*          tau    = (float*)(ws + (64 << 10));           //  64 KB
    float*          eres   = (float*)(ws + (128 << 10));          //  64 KB
    float*          EH     = (float*)(ws + (192 << 10));          //  16 B
    unsigned short* cnt_pb = (unsigned short*)(ws + (256 << 10)); // 256 KB
    unsigned short* xh     = (unsigned short*)(ws + (1 << 20));   //   2 MB
    unsigned short* buf2   = (unsigned short*)(ws + (5 << 20));   // 10.5 MB (16384*8*40*2)
    float*          part   = (float*)(ws + (5 << 20));            //   8 MB, ALIASES buf2:
    // part is written by tau_p and fully consumed by tau_m BEFORE filter_k writes buf2.

    hipLaunchKernelGGL(split_k,  dim3(1024), dim3(256), 0, stream, x, xh, nrm, eres);
    hipLaunchKernelGGL(red_k,    dim3(2),    dim3(256), 0, stream, nrm, eres, EH);
    hipLaunchKernelGGL(tau_p,    dim3(512),  dim3(256), 0, stream, xh, nrm, part);
    hipLaunchKernelGGL(tau_m,    dim3(256),  dim3(64),  0, stream, part, nrm, eres, EH, tau);
    hipLaunchKernelGGL(filter_k, dim3(1024), dim3(256), 0, stream, xh, nrm, tau, cnt_pb, buf2);
    hipLaunchKernelGGL(rerank_k, dim3(4096), dim3(256), 0, stream, x, cnt_pb, buf2, out);
}